// Round 2
// baseline (1692.949 us; speedup 1.0000x reference)
//
#include <hip/hip_runtime.h>

// Bit-exact gold model (VERIFIED rounds 12-13, absmax=0): per C element the
// GEMM is 4 panels of 512 sequential fmaf's (k ascending, single acc); panel
// sums folded ((p0+p1)+p2)+p3; then bias add; elementwise = one rounded fp32
// op per ufunc, contract(off).
// Round 16 (= round 15 resubmit, infra failure): A-in-SGPR GEMM (single-wave
// blocks, uniform s_load for A rows; v_fma v,s,v,v), B-only in LDS
// (0.25 B/FMA, conflict-free contiguous reads), global_load_lds double-buffer
// with counted vmcnt(8), no barriers. 32 outputs/thread -> 2048 waves ->
// 2 waves/SIMD. Hardened: sched_barrier(0) after asm waitcnt (rule #18),
// uintptr_t address-space casts.

#pragma clang fp contract(off)

#define B_ROWS 512
#define N_OUT 2048
#define K_IN 2048
#define NSTEP 16
#define NPANEL 4
#define PANK 512
#define BK 16
#define TM 16
#define TN 128
#define NTILES (PANK / BK)   // 32

typedef const __attribute__((address_space(1))) void* gptr_t;
typedef __attribute__((address_space(3))) void* lptr_t;

// ---- 32x32 LDS-tiled transpose: WT[k][n] = W[n][k] (*mask) ----
__global__ __launch_bounds__(256) void transpose_tile(
    const float* __restrict__ W, const int* __restrict__ mask,
    float* __restrict__ WT, int useMask)
{
    __shared__ float t[32][33];
    int kb = blockIdx.x * 32, nb = blockIdx.y * 32;
    int tx = threadIdx.x, ty = threadIdx.y;   // block (32, 8)
#pragma unroll
    for (int r = 0; r < 32; r += 8) {
        size_t src = (size_t)(nb + ty + r) * K_IN + (kb + tx);
        float v = W[src];
        if (useMask) v *= (float)mask[src];   // mask in {0,1}: exact
        t[ty + r][tx] = v;
    }
    __syncthreads();
#pragma unroll
    for (int r = 0; r < 32; r += 8)
        WT[(size_t)(kb + ty + r) * N_OUT + (nb + tx)] = t[tx][ty + r];
}

__global__ __launch_bounds__(256) void init_state(float* mem, float* ath,
                                                  float* ssum, float* spk) {
    int idx = blockIdx.x * 256 + threadIdx.x;
    mem[idx] = 0.0f; ath[idx] = 0.0f; ssum[idx] = 0.0f; spk[idx] = 0.0f;
}

// ---- one K-panel of C = A @ BT : Cp[panel][m][n], bit-exact 512-chain ----
// Single wave per block. TM=16 rows via uniform scalar loads (SGPR operand
// in v_fma), TN=128 cols: lane owns cols n0+lane*2, n0+lane*2+1.
__global__ __launch_bounds__(64, 2) void gemm_panel(
    const float* __restrict__ A,    // [512][2048] (x or spk)
    const float* __restrict__ BT,   // [2048][2048] (WT)
    float* __restrict__ Cp)         // [4][512][2048]
{
    __shared__ float Bs[2][BK][TN];   // 16 KB, rows contiguous (no pad):
                                      // reads are lane-contiguous -> conflict-free
    const int lane = threadIdx.x;
    const int n0 = blockIdx.x * TN;
    const int m0 = blockIdx.y * TM;
    const int pan = blockIdx.z;
    const int kbase = pan * PANK;

    float acc[TM][2];
#pragma unroll
    for (int i = 0; i < TM; i++) { acc[i][0] = 0.0f; acc[i][1] = 0.0f; }

    // per-lane global source for staging: 2 rows per global_load_lds
    // (64 lanes x 16B = 1024B = 2 x 512B rows of the B tile)
    const float* src0 = BT + (size_t)(kbase + (lane >> 5)) * N_OUT
                           + n0 + (lane & 31) * 4;

    // prologue: stage kt=0 into buf 0  (8 x global_load_lds dwordx4)
#pragma unroll
    for (int i = 0; i < 8; i++)
        __builtin_amdgcn_global_load_lds(
            (gptr_t)(uintptr_t)(src0 + (size_t)(i * 2) * N_OUT),
            (lptr_t)(uintptr_t)&Bs[0][i * 2][0], 16, 0, 0);

    int buf = 0;
    for (int kt = 0; kt < NTILES; kt++) {
        if (kt + 1 < NTILES) {
            // issue next tile's staging first; counted wait leaves it in flight
#pragma unroll
            for (int i = 0; i < 8; i++)
                __builtin_amdgcn_global_load_lds(
                    (gptr_t)(uintptr_t)(src0 + (size_t)((kt + 1) * BK + i * 2) * N_OUT),
                    (lptr_t)(uintptr_t)&Bs[buf ^ 1][i * 2][0], 16, 0, 0);
            asm volatile("s_waitcnt vmcnt(8)" ::: "memory");  // cur buf ready
            __builtin_amdgcn_sched_barrier(0);
        } else {
            asm volatile("s_waitcnt vmcnt(0)" ::: "memory");
            __builtin_amdgcn_sched_barrier(0);
        }

        // B fragments for all 16 kk: contiguous 512B wave reads, no conflicts
        float2 bv[BK];
#pragma unroll
        for (int kk = 0; kk < BK; kk++)
            bv[kk] = *(const float2*)&Bs[buf][kk][lane * 2];

        // A: 4 groups of 4 rows; addresses are block-uniform -> s_load to SGPR
        const float* Akt = A + (size_t)m0 * K_IN + kbase + kt * BK;
#pragma unroll
        for (int mg = 0; mg < 4; mg++) {
            float av[4][BK];
#pragma unroll
            for (int r = 0; r < 4; r++) {
                const float* Ar = Akt + (size_t)(mg * 4 + r) * K_IN;
                float4 q0 = *(const float4*)(Ar + 0);
                float4 q1 = *(const float4*)(Ar + 4);
                float4 q2 = *(const float4*)(Ar + 8);
                float4 q3 = *(const float4*)(Ar + 12);
                av[r][0]  = q0.x; av[r][1]  = q0.y; av[r][2]  = q0.z; av[r][3]  = q0.w;
                av[r][4]  = q1.x; av[r][5]  = q1.y; av[r][6]  = q1.z; av[r][7]  = q1.w;
                av[r][8]  = q2.x; av[r][9]  = q2.y; av[r][10] = q2.z; av[r][11] = q2.w;
                av[r][12] = q3.x; av[r][13] = q3.y; av[r][14] = q3.z; av[r][15] = q3.w;
            }
            // kk ascending => each acc element's 512-chain stays in gold order
#pragma unroll
            for (int kk = 0; kk < BK; kk++) {
                float bx = bv[kk].x, by = bv[kk].y;
#pragma unroll
                for (int r = 0; r < 4; r++) {
                    acc[mg * 4 + r][0] = fmaf(av[r][kk], bx, acc[mg * 4 + r][0]);
                    acc[mg * 4 + r][1] = fmaf(av[r][kk], by, acc[mg * 4 + r][1]);
                }
            }
        }
        buf ^= 1;
    }

    const size_t P = (size_t)B_ROWS * N_OUT;
#pragma unroll
    for (int i = 0; i < TM; i++) {
        size_t off = (size_t)pan * P + (size_t)(m0 + i) * N_OUT + n0 + lane * 2;
        *(float2*)(Cp + off) = make_float2(acc[i][0], acc[i][1]);
    }
}

// ---- ff = fold(Cp) + b_fc  (bit-exact ordered fold) ----
__global__ __launch_bounds__(256) void ff_fold(
    const float* __restrict__ Cp, const float* __restrict__ b_fc,
    float* __restrict__ ff)
{
    const size_t P = (size_t)B_ROWS * N_OUT;
    size_t base = ((size_t)blockIdx.x * 256 + threadIdx.x) * 4;
    int n = (int)(base & (N_OUT - 1));
    float4 p0 = *(const float4*)(Cp + base);
    float4 p1 = *(const float4*)(Cp + P + base);
    float4 p2 = *(const float4*)(Cp + 2 * P + base);
    float4 p3 = *(const float4*)(Cp + 3 * P + base);
    float4 bv = *(const float4*)(b_fc + n);
    float4 o;
    o.x = (((p0.x + p1.x) + p2.x) + p3.x) + bv.x;
    o.y = (((p0.y + p1.y) + p2.y) + p3.y) + bv.y;
    o.z = (((p0.z + p1.z) + p2.z) + p3.z) + bv.z;
    o.w = (((p0.w + p1.w) + p2.w) + p3.w) + bv.w;
    *(float4*)(ff + base) = o;
}

// ---- fold(Cp) + b_rec -> memr, then fused fp32 SNN elementwise update ----
__global__ __launch_bounds__(256) void fold_update(
    const float* __restrict__ Cp, const float* __restrict__ b_rec,
    const float* __restrict__ spk_in, const float* __restrict__ ff,
    float* __restrict__ mem, float* __restrict__ ath,
    float* __restrict__ ssum, float* __restrict__ spk_out,
    float* __restrict__ out, int last)
{
    const size_t P = (size_t)B_ROWS * N_OUT;
    size_t base = ((size_t)blockIdx.x * 256 + threadIdx.x) * 4;
    int n = (int)(base & (N_OUT - 1));
    float4 p0 = *(const float4*)(Cp + base);
    float4 p1 = *(const float4*)(Cp + P + base);
    float4 p2 = *(const float4*)(Cp + 2 * P + base);
    float4 p3 = *(const float4*)(Cp + 3 * P + base);
    float4 bv = *(const float4*)(b_rec + n);
    float4 sv = *(const float4*)(spk_in + base);
    float4 av = *(const float4*)(ath + base);
    float4 mv = *(const float4*)(mem + base);
    float4 fv = *(const float4*)(ff + base);
    float4 uv = *(const float4*)(ssum + base);

    float cr[4] = {(((p0.x + p1.x) + p2.x) + p3.x),
                   (((p0.y + p1.y) + p2.y) + p3.y),
                   (((p0.z + p1.z) + p2.z) + p3.z),
                   (((p0.w + p1.w) + p2.w) + p3.w)};
    float ba[4] = {bv.x, bv.y, bv.z, bv.w};
    float sa[4] = {sv.x, sv.y, sv.z, sv.w};
    float aa[4] = {av.x, av.y, av.z, av.w};
    float ma[4] = {mv.x, mv.y, mv.z, mv.w};
    float fa[4] = {fv.x, fv.y, fv.z, fv.w};
    float ua[4] = {uv.x, uv.y, uv.z, uv.w};
    float mo[4], ao[4], uo[4], so[4];
#pragma unroll
    for (int j = 0; j < 4; j++) {
        float memr  = cr[j] + ba[j];      // rounded add
        float sp    = sa[j];
        float t1    = aa[j] * 0.9f;       // rounded
        float t2    = 0.5f * sp;          // exact
        float athn  = t1 + t2;            // rounded
        float u1    = ma[j] * 0.2f;       // rounded
        float u2    = 1.0f - sp;          // exact {1,0,-1}
        float u3    = u1 * u2;            // exact (sign/zero)
        float u4    = u3 + fa[j];         // rounded
        float u5    = athn * 0.2f;        // rounded
        float memff = u4 - u5;            // rounded
        float s_ff  = (memff > 0.5f) ? 1.0f : 0.0f;
        float s_r   = (memr  > 0.5f) ? 1.0f : 0.0f;
        mo[j] = memff + memr;             // rounded
        ao[j] = athn;
        so[j] = s_ff + s_r;               // exact
        uo[j] = ua[j] + so[j];            // exact (small ints)
    }
    *(float4*)(mem + base)     = make_float4(mo[0], mo[1], mo[2], mo[3]);
    *(float4*)(ath + base)     = make_float4(ao[0], ao[1], ao[2], ao[3]);
    *(float4*)(ssum + base)    = make_float4(uo[0], uo[1], uo[2], uo[3]);
    *(float4*)(spk_out + base) = make_float4(so[0], so[1], so[2], so[3]);
    if (last)
        *(float4*)(out + base) = make_float4(uo[0], uo[1], uo[2], uo[3]);
}

extern "C" void kernel_launch(void* const* d_in, const int* in_sizes, int n_in,
                              void* d_out, int out_size, void* d_ws, size_t ws_size,
                              hipStream_t stream) {
    const float* x      = (const float*)d_in[0];
    const float* W_fc   = (const float*)d_in[1];
    const float* b_fc   = (const float*)d_in[2];
    const float* W_rec  = (const float*)d_in[3];
    const float* b_rec  = (const float*)d_in[4];
    const int*   rmask  = (const int*)d_in[5];
    // d_in[6] = spike_window (16)

    char* ws = (char*)d_ws;
    float* WT   = (float*)(ws);                    // 16 MB (fc, then rec)
    float* ff   = (float*)(ws + (16u << 20));      //  4 MB
    float* mem  = (float*)(ws + (20u << 20));      //  4 MB
    float* ath  = (float*)(ws + (24u << 20));      //  4 MB
    float* ssum = (float*)(ws + (28u << 20));      //  4 MB
    float* spkA = (float*)(ws + (32u << 20));      //  4 MB
    float* spkB = (float*)(ws + (36u << 20));      //  4 MB
    float* Cp   = (float*)(ws + (40u << 20));      // 16 MB (total 56 MB)

    dim3 gridT(K_IN / 32, N_OUT / 32);             // (64, 64)
    dim3 blkT(32, 8);
    dim3 gridS((B_ROWS * N_OUT) / 256);            // 4096
    dim3 gridG(N_OUT / TN, B_ROWS / TM, NPANEL);   // (16, 32, 4) = 2048 blocks
    dim3 gridF((B_ROWS * N_OUT) / (256 * 4));      // 1024

    transpose_tile<<<gridT, blkT, 0, stream>>>(W_fc, rmask, WT, 0);
    init_state<<<gridS, 256, 0, stream>>>(mem, ath, ssum, spkA);
    gemm_panel<<<gridG, 64, 0, stream>>>(x, WT, Cp);
    ff_fold<<<gridF, 256, 0, stream>>>(Cp, b_fc, ff);
    transpose_tile<<<gridT, blkT, 0, stream>>>(W_rec, rmask, WT, 1);

    for (int t = 0; t < NSTEP; t++) {
        const float* si = (t & 1) ? spkB : spkA;
        float*       so = (t & 1) ? spkA : spkB;
        gemm_panel<<<gridG, 64, 0, stream>>>(si, WT, Cp);
        fold_update<<<gridF, 256, 0, stream>>>(
            Cp, b_rec, si, ff, mem, ath, ssum, so, (float*)d_out, t == NSTEP - 1);
    }
}